// Round 9
// baseline (687.031 us; speedup 1.0000x reference)
//
#include <hip/hip_runtime.h>
#include <math.h>

#define SEQ 8192
#define DIM 1024
#define NBATCH 8

typedef float vf4 __attribute__((ext_vector_type(4)));

struct SDesc {
  int n, Tmax, totalRows;
  int pos[8], A[8], rowbase[8];
  int anc[8][8];
  float cnt[8][8];
  int nu;
  int upos[16];
  int up_of_s[8];
  int s_of_rr[32], a_of_rr[32], ua_of_rr[32];
};

// Host-side faithful reimplementation of _gen_spine/_analyze/_structures,
// including the levels[lvl+1] OVERWRITE semantics of the reference BFS.
static SDesc build_structs() {
  SDesc H{};
  int spine[24];
  int ns = 3; spine[0] = 0; spine[1] = 2; spine[2] = 4;
  for (;;) {
    long nxt = 2L * (spine[ns-1] + spine[ns-2] + spine[ns-3]);
    if (nxt >= SEQ) break;
    spine[ns++] = (int)nxt;
  }
  int rb = 0;
  for (int i = 0; i < ns; ++i) {
    int pos = spine[i];
    if (pos < 3) continue;
    bool visited[24] = {false};
    int levels[12][8]; int lcnt[12];
    for (int l = 0; l < 12; ++l) lcnt[l] = 0;
    levels[0][0] = i; lcnt[0] = 1; visited[i] = true;
    int qidx[64], qlvl[64], qh = 0, qt = 0;
    qidx[qt] = i; qlvl[qt] = 0; qt++;
    int maxd = 0;
    while (qh < qt) {
      int cur = qidx[qh], lvl = qlvl[qh]; qh++;
      if (lvl >= 9) break;
      int newl[8], nn = 0;
      if (cur >= 3) {
        for (int d = 1; d <= 3; ++d) {
          int a = cur - d;
          if (!visited[a]) { visited[a] = true; newl[nn++] = a; qidx[qt] = a; qlvl[qt] = lvl + 1; qt++; }
        }
      }
      if (nn) {
        lcnt[lvl+1] = nn;
        for (int k = 0; k < nn; ++k) levels[lvl+1][k] = newl[k];
        if (lvl + 1 > maxd) maxd = lvl + 1;
      }
    }
    float pcv[24]; bool pcs[24];
    for (int k = 0; k < 24; ++k) { pcv[k] = 0.f; pcs[k] = false; }
    pcv[i] = 1.f; pcs[i] = true;
    for (int lvl = maxd; lvl >= 0; --lvl) {
      for (int nidx = 0; nidx < lcnt[lvl]; ++nidx) {
        int node = levels[lvl][nidx];
        if (node == i) continue;
        if (lvl == maxd) { pcv[node] = 1.f; pcs[node] = true; continue; }
        float c = 0.f;
        for (int cidx = 0; cidx < lcnt[lvl+1]; ++cidx) {
          int ch = levels[lvl+1][cidx];
          if (ch >= 3 && node >= ch - 3 && node <= ch - 1) c += pcs[ch] ? pcv[ch] : 0.f;
        }
        if (lvl != 0) { pcv[node] = c; pcs[node] = true; }
      }
    }
    int A = 0;
    int sidx = H.n;
    for (int lvl = 1; lvl <= maxd; ++lvl) {
      for (int nidx = 0; nidx < lcnt[lvl]; ++nidx) {
        int node = levels[lvl][nidx];
        H.anc[sidx][A] = spine[node];
        H.cnt[sidx][A] = pcs[node] ? pcv[node] : 1.f;
        A++;
      }
    }
    if (A == 0) continue;
    H.pos[sidx] = pos; H.A[sidx] = A; H.rowbase[sidx] = rb; rb += A;
    H.n++;
  }
  H.totalRows = rb;
  H.Tmax = 0;
  for (int s = 0; s < H.n; ++s) if (H.A[s] > H.Tmax) H.Tmax = H.A[s];
  int vals[128], nv = 0;
  for (int s = 0; s < H.n; ++s) {
    vals[nv++] = H.pos[s];
    for (int a = 0; a < H.A[s]; ++a) vals[nv++] = H.anc[s][a];
  }
  H.nu = 0;
  for (int i = 0; i < nv; ++i) {
    bool seen = false;
    for (int u = 0; u < H.nu; ++u) if (H.upos[u] == vals[i]) { seen = true; break; }
    if (!seen) H.upos[H.nu++] = vals[i];
  }
  for (int i = 0; i < H.nu; ++i)
    for (int j2 = i + 1; j2 < H.nu; ++j2)
      if (H.upos[j2] < H.upos[i]) { int t = H.upos[i]; H.upos[i] = H.upos[j2]; H.upos[j2] = t; }
  auto uidx = [&](int v) { for (int u = 0; u < H.nu; ++u) if (H.upos[u] == v) return u; return 0; };
  for (int s = 0; s < H.n; ++s) {
    H.up_of_s[s] = uidx(H.pos[s]);
    for (int a = 0; a < H.A[s]; ++a) {
      int rr = H.rowbase[s] + a;
      H.s_of_rr[rr] = s; H.a_of_rr[rr] = a; H.ua_of_rr[rr] = uidx(H.anc[s][a]);
    }
  }
  return H;
}

// ---------------- device helpers ----------------

__device__ __forceinline__ float wred(float v) {
  #pragma unroll
  for (int off = 32; off; off >>= 1) v += __shfl_xor(v, off);
  return v;
}

__device__ __forceinline__ float dot4(vf4 a, vf4 b) {
  return a.x * b.x + a.y * b.y + a.z * b.z + a.w * b.w;
}

__device__ __forceinline__ void do_copy(const vf4* __restrict__ src, vf4* __restrict__ dst,
                                        int q, int nc, int start4, int n4) {
  for (int i = q * 256 + threadIdx.x; i < n4; i += nc * 256) {
    vf4 v = __builtin_nontemporal_load(&src[start4 + i]);
    __builtin_nontemporal_store(v, &dst[start4 + i]);
  }
}

// software grid barrier among co-resident blocks (agent scope: cross-XCD L2 coherence)
__device__ __forceinline__ void gsync(int* c, int target) {
  __syncthreads();
  if (threadIdx.x == 0) {
    __hip_atomic_fetch_add(c, 1, __ATOMIC_RELEASE, __HIP_MEMORY_SCOPE_AGENT);
    int it = 0;
    while (__hip_atomic_load(c, __ATOMIC_ACQUIRE, __HIP_MEMORY_SCOPE_AGENT) < target) {
      __builtin_amdgcn_s_sleep(8);
      if (++it > (1 << 20)) break;   // bailout: bug -> wrong answer, not hang
    }
  }
  __syncthreads();
}

__device__ __forceinline__ void garrive(int* c) {
  __syncthreads();
  if (threadIdx.x == 0)
    __hip_atomic_fetch_add(c, 1, __ATOMIC_RELEASE, __HIP_MEMORY_SCOPE_AGENT);
}

// ---------------- kernel 1: T matmul + pw-prep + copy ----------------
// mains 0..1279 (128 j-tiles x 10 row-tiles), block 1280 = prep, 2048 carriers.
__global__ __launch_bounds__(256, 4) void k_T(SDesc sd, const float* __restrict__ x,
    const float* __restrict__ msg_w, float* __restrict__ T,
    const float* __restrict__ w1, const float* __restrict__ b1,
    const float* __restrict__ w2, const float* __restrict__ b2, float* __restrict__ wout,
    const vf4* __restrict__ csrc, vf4* __restrict__ cdst, int cstart, int cn) {
  int p = blockIdx.x;
  const int NMAIN = 1280;
  if (p > NMAIN) { do_copy(csrc, cdst, p - NMAIN - 1, 2048, cstart, cn); return; }
  if (p == NMAIN) {
    int t = threadIdx.x;
    int s = t >> 3, a = t & 7;
    if (t < 64 && s < sd.n && a < sd.A[s]) {
      float v = sd.cnt[s][a];
      float acc = 0.f;
      for (int i = 0; i < 64; ++i) {
        float h = v * w1[i] + b1[i];
        if (h > 0.f) acc += h * w2[i];
      }
      float o = acc + b2[0];
      wout[s * 8 + a] = (o > 0.f) ? (o + log1pf(expf(-o))) : log1pf(expf(o));
    }
    return;
  }
  int q = p % 128, rt = p / 128;          // rt 0..9
  int jt = (q & 7) * 16 + (q >> 3);       // XCD-pinned
  int wave = threadIdx.x >> 6, lane = threadIdx.x & 63;
  int jc0 = jt * 16 + wave * 4;
  const vf4* mw4 = (const vf4*)msg_w;
  size_t wb0 = (size_t)((jc0 + 0) & 1023) * 512 + ((size_t)((jc0 + 0) >> 10) << 8);
  size_t wb1 = (size_t)((jc0 + 1) & 1023) * 512 + ((size_t)((jc0 + 1) >> 10) << 8);
  size_t wb2 = (size_t)((jc0 + 2) & 1023) * 512 + ((size_t)((jc0 + 2) >> 10) << 8);
  size_t wb3 = (size_t)((jc0 + 3) & 1023) * 512 + ((size_t)((jc0 + 3) >> 10) << 8);
  vf4 tw0[4], tw1[4], tw2[4], tw3[4];
  #pragma unroll
  for (int c = 0; c < 4; ++c) {
    tw0[c] = mw4[wb0 + c * 64 + lane];
    tw1[c] = mw4[wb1 + c * 64 + lane];
    tw2[c] = mw4[wb2 + c * 64 + lane];
    tw3[c] = mw4[wb3 + c * 64 + lane];
  }
  const vf4* x4 = (const vf4*)x;
  #pragma unroll 2
  for (int r = 0; r < 8; ++r) {
    int row = rt * 8 + r; int uq = row >> 3, bb = row & 7;
    size_t rb4 = ((size_t)bb * SEQ + sd.upos[uq]) * 256;
    vf4 a0 = x4[rb4 + 0 * 64 + lane], a1 = x4[rb4 + 1 * 64 + lane];
    vf4 a2 = x4[rb4 + 2 * 64 + lane], a3 = x4[rb4 + 3 * 64 + lane];
    float s0 = dot4(tw0[0], a0) + dot4(tw0[1], a1) + dot4(tw0[2], a2) + dot4(tw0[3], a3);
    float s1 = dot4(tw1[0], a0) + dot4(tw1[1], a1) + dot4(tw1[2], a2) + dot4(tw1[3], a3);
    float s2 = dot4(tw2[0], a0) + dot4(tw2[1], a1) + dot4(tw2[2], a2) + dot4(tw2[3], a3);
    float s3 = dot4(tw3[0], a0) + dot4(tw3[1], a1) + dot4(tw3[2], a2) + dot4(tw3[3], a3);
    s0 = wred(s0); s1 = wred(s1); s2 = wred(s2); s3 = wred(s3);
    if (lane == 0) {
      float* tp = T + (size_t)row * 2048 + jc0;
      tp[0] = s0; tp[1] = s1; tp[2] = s2; tp[3] = s3;
    }
  }
}

// ---------------- kernel 2: LN -> barrier -> gi  (+copy) ----------------
// mains 0..959; barrier among 960 (co-resident <=1024; carriers retire).
__global__ __launch_bounds__(256, 4) void k_lngi(SDesc sd, const float* __restrict__ ln_g,
    const float* __restrict__ ln_b, const float* __restrict__ msg_b,
    const float* __restrict__ wsc, const float* __restrict__ T, float* __restrict__ mseq,
    const float* __restrict__ wih, const float* __restrict__ bih, float* __restrict__ gi,
    int* __restrict__ bar,
    const vf4* __restrict__ csrc, vf4* __restrict__ cdst, int cstart, int cn) {
  int p = blockIdx.x;
  const int NM = 960;
  if (p >= NM) { do_copy(csrc, cdst, p - NM, 2048, cstart, cn); return; }
  int wave = threadIdx.x >> 6, lane = threadIdx.x & 63;

  if (p < 240) {
    int rr = p >> 3, bb = p & 7;
    int s = sd.s_of_rr[rr], aa = sd.a_of_rr[rr];
    int ua = sd.ua_of_rr[rr], up = sd.up_of_s[s];
    float wmul = wsc[s * 8 + aa];
    const vf4* Tl = (const vf4*)(T + ((size_t)ua * 8 + bb) * 2048);
    const vf4* Tr = (const vf4*)(T + ((size_t)up * 8 + bb) * 2048 + 1024);
    const vf4* mb = (const vf4*)msg_b;
    int t = threadIdx.x;
    vf4 vl = Tl[t], vr = Tr[t], vb = mb[t];
    vf4 v; v.x = vl.x + vr.x + vb.x; v.y = vl.y + vr.y + vb.y;
    v.z = vl.z + vr.z + vb.z; v.w = vl.w + vr.w + vb.w;
    float sum = v.x + v.y + v.z + v.w;
    float sq  = v.x * v.x + v.y * v.y + v.z * v.z + v.w * v.w;
    #pragma unroll
    for (int off = 32; off; off >>= 1) { sum += __shfl_xor(sum, off); sq += __shfl_xor(sq, off); }
    __shared__ float s1m[4], s2m[4];
    if (lane == 0) { s1m[wave] = sum; s2m[wave] = sq; }
    __syncthreads();
    sum = s1m[0] + s1m[1] + s1m[2] + s1m[3];
    sq  = s2m[0] + s2m[1] + s2m[2] + s2m[3];
    float mu  = sum * (1.f / 1024.f);
    float var = sq * (1.f / 1024.f) - mu * mu;
    float inv = rsqrtf(var + 1e-5f);
    vf4 g4 = ((const vf4*)ln_g)[t];
    vf4 b4 = ((const vf4*)ln_b)[t];
    float o[4]  = {v.x, v.y, v.z, v.w};
    float gg[4] = {g4.x, g4.y, g4.z, g4.w};
    float bb2[4] = {b4.x, b4.y, b4.z, b4.w};
    #pragma unroll
    for (int i = 0; i < 4; ++i) {
      float u = (o[i] - mu) * inv * gg[i] + bb2[i];
      float ge = 0.5f * u * (1.f + erff(u * 0.70710678118654752f));
      o[i] = ge * wmul;
    }
    vf4 ov; ov.x = o[0]; ov.y = o[1]; ov.z = o[2]; ov.w = o[3];
    ((vf4*)(mseq + (size_t)p * DIM))[t] = ov;
  }

  gsync(&bar[0], NM);

  // gi: 192 j-tiles(16 j) x 5 row-tiles(48 rows)
  int q = p % 192, rt = p / 192;
  int jt = (q & 7) * 24 + (q >> 3);
  int j0 = jt * 16 + wave * 4;
  const vf4* wp4 = (const vf4*)wih;
  vf4 w0[4], w1[4], w2[4], w3[4];
  #pragma unroll
  for (int c = 0; c < 4; ++c) {
    w0[c] = wp4[(size_t)(j0 + 0) * 256 + c * 64 + lane];
    w1[c] = wp4[(size_t)(j0 + 1) * 256 + c * 64 + lane];
    w2[c] = wp4[(size_t)(j0 + 2) * 256 + c * 64 + lane];
    w3[c] = wp4[(size_t)(j0 + 3) * 256 + c * 64 + lane];
  }
  const vf4* m4 = (const vf4*)mseq;
  for (int r = 0; r < 48; ++r) {
    int row = rt * 48 + r;
    size_t rb4 = (size_t)row * 256;
    vf4 a0 = m4[rb4 + 0 * 64 + lane], a1 = m4[rb4 + 1 * 64 + lane];
    vf4 a2 = m4[rb4 + 2 * 64 + lane], a3 = m4[rb4 + 3 * 64 + lane];
    float s0 = dot4(w0[0], a0) + dot4(w0[1], a1) + dot4(w0[2], a2) + dot4(w0[3], a3);
    float s1 = dot4(w1[0], a0) + dot4(w1[1], a1) + dot4(w1[2], a2) + dot4(w1[3], a3);
    float s2 = dot4(w2[0], a0) + dot4(w2[1], a1) + dot4(w2[2], a2) + dot4(w2[3], a3);
    float s3 = dot4(w3[0], a0) + dot4(w3[1], a1) + dot4(w3[2], a2) + dot4(w3[3], a3);
    s0 = wred(s0); s1 = wred(s1); s2 = wred(s2); s3 = wred(s3);
    if (lane == 0) {
      float* gp = gi + (size_t)row * 3072;
      gp[j0 + 0] = s0 + bih[j0 + 0]; gp[j0 + 1] = s1 + bih[j0 + 1];
      gp[j0 + 2] = s2 + bih[j0 + 2]; gp[j0 + 3] = s3 + bih[j0 + 3];
    }
  }
}

// ---------------- kernel 3: GRU t=0..4 + gate  (+copy) ----------------
// mains 0..511: wave owns j=(p&255)*4+wave; row-parity hb=p>>8.
// 1024 carriers copy then arrive at final counter; gate (blocks 0..127) waits
// for mains+carriers so its pos-row writes land after the copy.
__global__ __launch_bounds__(256, 4) void k_steps(SDesc sd,
    const float* __restrict__ whh, const float* __restrict__ bhh,
    const float* __restrict__ gi, float* __restrict__ h0, float* __restrict__ h1,
    const float* __restrict__ x, const float* __restrict__ gw,
    const float* __restrict__ gb, float* __restrict__ out,
    int* __restrict__ bar,
    const vf4* __restrict__ csrc, vf4* __restrict__ cdst, int cstart, int cn) {
  int p = blockIdx.x;
  const int NM = 512;
  if (p >= NM) {
    do_copy(csrc, cdst, p - NM, 1024, cstart, cn);
    garrive(&bar[5]);
    return;
  }
  int wave = threadIdx.x >> 6, lane = threadIdx.x & 63;
  int j = (p & 255) * 4 + wave;
  int hb = p >> 8;
  const vf4* wp4 = (const vf4*)whh;
  vf4 wr[4], wz[4], wn[4];
  #pragma unroll
  for (int c = 0; c < 4; ++c) {
    wr[c] = wp4[(size_t)j * 256 + c * 64 + lane];
    wz[c] = wp4[(size_t)(1024 + j) * 256 + c * 64 + lane];
    wn[c] = wp4[(size_t)(2048 + j) * 256 + c * 64 + lane];
  }
  float bj_r = bhh[j], bj_z = bhh[1024 + j], bj_n = bhh[2048 + j];

  for (int t = 0; t < 5; ++t) {
    const float* hold = (t & 1) ? h1 : h0;   // t=0 hold unused
    float*       hnew = (t & 1) ? h0 : h1;   // final (t=4) -> h1
    const vf4* h4 = (const vf4*)hold;
    for (int sr = hb; sr < 56; sr += 2) {
      int s = sr >> 3, r = sr & 7;
      if (s >= sd.n) continue;
      int t0 = sd.Tmax - sd.A[s];
      if (t < t0) continue;
      int a = t - t0;
      int srow = s * 8 + r;
      const float* gp = gi + (size_t)((sd.rowbase[s] + a) * 8 + r) * 3072;
      if (a == 0) {
        if (lane == 0) {
          float rg = 1.f / (1.f + expf(-(gp[j] + bj_r)));
          float zg = 1.f / (1.f + expf(-(gp[1024 + j] + bj_z)));
          float ng = tanhf(gp[2048 + j] + rg * bj_n);
          hnew[(size_t)srow * DIM + j] = (1.f - zg) * ng;
        }
        continue;
      }
      size_t rb4 = (size_t)srow * 256;
      float gir = gp[j], giz = gp[1024 + j], gin = gp[2048 + j];
      vf4 a0 = h4[rb4 + 0 * 64 + lane], a1 = h4[rb4 + 1 * 64 + lane];
      vf4 a2 = h4[rb4 + 2 * 64 + lane], a3 = h4[rb4 + 3 * 64 + lane];
      float ar = dot4(wr[0], a0) + dot4(wr[1], a1) + dot4(wr[2], a2) + dot4(wr[3], a3);
      float az = dot4(wz[0], a0) + dot4(wz[1], a1) + dot4(wz[2], a2) + dot4(wz[3], a3);
      float an = dot4(wn[0], a0) + dot4(wn[1], a1) + dot4(wn[2], a2) + dot4(wn[3], a3);
      ar = wred(ar); az = wred(az); an = wred(an);
      if (lane == 0) {
        float rg = 1.f / (1.f + expf(-(gir + ar + bj_r)));
        float zg = 1.f / (1.f + expf(-(giz + az + bj_z)));
        float ng = tanhf(gin + rg * (an + bj_n));
        float ho = hold[(size_t)srow * DIM + j];
        hnew[(size_t)srow * DIM + j] = (1.f - zg) * ng + zg * ho;
      }
    }
    if (t < 4) gsync(&bar[1 + t], NM);
  }

  // final barrier: mains + carriers (copy of pos rows must precede gate writes)
  if (p >= 128) { garrive(&bar[5]); return; }
  gsync(&bar[5], NM + 1024);

  // gate: blocks 0..127, 2 j per wave, all 56 rows
  int j0 = p * 8 + wave * 2;
  const vf4* g4p = (const vf4*)gw;
  vf4 wL0[4], wR0[4], wL1[4], wR1[4];
  #pragma unroll
  for (int c = 0; c < 4; ++c) {
    wL0[c] = g4p[(size_t)(j0 + 0) * 512 + c * 64 + lane];
    wR0[c] = g4p[(size_t)(j0 + 0) * 512 + 256 + c * 64 + lane];
    wL1[c] = g4p[(size_t)(j0 + 1) * 512 + c * 64 + lane];
    wR1[c] = g4p[(size_t)(j0 + 1) * 512 + 256 + c * 64 + lane];
  }
  const vf4* h4 = (const vf4*)h1;
  const vf4* x4 = (const vf4*)x;
  for (int row = 0; row < 56; ++row) {
    int s = row >> 3, bb = row & 7;
    size_t ab4 = (size_t)row * 256;
    size_t xb4 = ((size_t)bb * SEQ + sd.pos[s]) * 256;
    vf4 a0 = h4[ab4 + 0 * 64 + lane], a1 = h4[ab4 + 1 * 64 + lane];
    vf4 a2 = h4[ab4 + 2 * 64 + lane], a3 = h4[ab4 + 3 * 64 + lane];
    vf4 x0 = x4[xb4 + 0 * 64 + lane], x1 = x4[xb4 + 1 * 64 + lane];
    vf4 x2 = x4[xb4 + 2 * 64 + lane], x3 = x4[xb4 + 3 * 64 + lane];
    float s0 = dot4(wL0[0], a0) + dot4(wL0[1], a1) + dot4(wL0[2], a2) + dot4(wL0[3], a3)
             + dot4(wR0[0], x0) + dot4(wR0[1], x1) + dot4(wR0[2], x2) + dot4(wR0[3], x3);
    float s1 = dot4(wL1[0], a0) + dot4(wL1[1], a1) + dot4(wL1[2], a2) + dot4(wL1[3], a3)
             + dot4(wR1[0], x0) + dot4(wR1[1], x1) + dot4(wR1[2], x2) + dot4(wR1[3], x3);
    s0 = wred(s0); s1 = wred(s1);
    if (lane == 0) {
      #pragma unroll
      for (int jj = 0; jj < 2; ++jj) {
        int jq = j0 + jj;
        float sv = jj ? s1 : s0;
        float g = 1.f / (1.f + expf(-(sv + gb[jq])));
        float agg = h1[(size_t)row * DIM + jq];
        float hc  = x[((size_t)bb * SEQ + sd.pos[s]) * DIM + jq];
        out[((size_t)bb * SEQ + sd.pos[s]) * DIM + jq] = g * agg + (1.f - g) * hc;
      }
    }
  }
}

// ---------------- launch ----------------

extern "C" void kernel_launch(void* const* d_in, const int* in_sizes, int n_in,
                              void* d_out, int out_size, void* d_ws, size_t ws_size,
                              hipStream_t stream) {
  const float* x      = (const float*)d_in[0];
  const float* pw_w1  = (const float*)d_in[1];
  const float* pw_b1  = (const float*)d_in[2];
  const float* pw_w2  = (const float*)d_in[3];
  const float* pw_b2  = (const float*)d_in[4];
  const float* msg_w  = (const float*)d_in[5];
  const float* msg_b  = (const float*)d_in[6];
  const float* ln_g   = (const float*)d_in[7];
  const float* ln_b   = (const float*)d_in[8];
  const float* w_ih   = (const float*)d_in[9];
  const float* w_hh   = (const float*)d_in[10];
  const float* b_ih   = (const float*)d_in[11];
  const float* b_hh   = (const float*)d_in[12];
  const float* gate_w = (const float*)d_in[13];
  const float* gate_b = (const float*)d_in[14];
  float* out = (float*)d_out;
  float* ws  = (float*)d_ws;

  SDesc sd = build_structs();          // n=7, Tmax=5, totalRows=30, nu=10 for S=8192

  int*   bar  = (int*)ws;                              // 16 ints (64 B)
  float* wout = ws + 64;                               // 64 floats
  float* T    = wout + 64;                             // 80*2048
  float* mseq = T + (size_t)sd.nu * 8 * 2048;          // 240*1024
  float* gi   = mseq + (size_t)240 * DIM;              // 240*3072
  float* h0   = gi + (size_t)240 * 3072;               // 56*1024
  float* h1   = h0 + (size_t)sd.n * 8 * DIM;           // 56*1024

  const vf4* x4 = (const vf4*)x;
  vf4* out4 = (vf4*)out;
  const int TOTAL4 = (NBATCH * SEQ * DIM) / 4;         // 16,777,216
  const int c_T = 5730000, c_lngi = 5730000;
  const int c_steps = TOTAL4 - c_T - c_lngi;           // 5,317,216

  // zero barrier counters each call (graph-capturable)
  hipMemsetAsync(d_ws, 0, 64, stream);

  k_T<<<1281 + 2048, 256, 0, stream>>>(sd, x, msg_w, T, pw_w1, pw_b1, pw_w2, pw_b2, wout,
                                       x4, out4, 0, c_T);

  k_lngi<<<960 + 2048, 256, 0, stream>>>(sd, ln_g, ln_b, msg_b, wout, T, mseq,
                                         w_ih, b_ih, gi, bar,
                                         x4, out4, c_T, c_lngi);

  k_steps<<<512 + 1024, 256, 0, stream>>>(sd, w_hh, b_hh, gi, h0, h1,
                                          x, gate_w, gate_b, out, bar,
                                          x4, out4, c_T + c_lngi, c_steps);

  (void)in_sizes; (void)n_in; (void)out_size; (void)ws_size;
}

// Round 10
// 276.675 us; speedup vs baseline: 2.4832x; 2.4832x over previous
//
#include <hip/hip_runtime.h>
#include <math.h>

#define SEQ 8192
#define DIM 1024
#define NBATCH 8

typedef float vf4 __attribute__((ext_vector_type(4)));

struct SDesc {
  int n, Tmax, totalRows;
  int pos[8], A[8], rowbase[8];
  int anc[8][8];
  float cnt[8][8];
  int nu;
  int upos[16];
  int up_of_s[8];
  int s_of_rr[32], a_of_rr[32], ua_of_rr[32];
};

// Host-side faithful reimplementation of _gen_spine/_analyze/_structures,
// including the levels[lvl+1] OVERWRITE semantics of the reference BFS.
static SDesc build_structs() {
  SDesc H{};
  int spine[24];
  int ns = 3; spine[0] = 0; spine[1] = 2; spine[2] = 4;
  for (;;) {
    long nxt = 2L * (spine[ns-1] + spine[ns-2] + spine[ns-3]);
    if (nxt >= SEQ) break;
    spine[ns++] = (int)nxt;
  }
  int rb = 0;
  for (int i = 0; i < ns; ++i) {
    int pos = spine[i];
    if (pos < 3) continue;
    bool visited[24] = {false};
    int levels[12][8]; int lcnt[12];
    for (int l = 0; l < 12; ++l) lcnt[l] = 0;
    levels[0][0] = i; lcnt[0] = 1; visited[i] = true;
    int qidx[64], qlvl[64], qh = 0, qt = 0;
    qidx[qt] = i; qlvl[qt] = 0; qt++;
    int maxd = 0;
    while (qh < qt) {
      int cur = qidx[qh], lvl = qlvl[qh]; qh++;
      if (lvl >= 9) break;
      int newl[8], nn = 0;
      if (cur >= 3) {
        for (int d = 1; d <= 3; ++d) {
          int a = cur - d;
          if (!visited[a]) { visited[a] = true; newl[nn++] = a; qidx[qt] = a; qlvl[qt] = lvl + 1; qt++; }
        }
      }
      if (nn) {
        lcnt[lvl+1] = nn;
        for (int k = 0; k < nn; ++k) levels[lvl+1][k] = newl[k];
        if (lvl + 1 > maxd) maxd = lvl + 1;
      }
    }
    float pcv[24]; bool pcs[24];
    for (int k = 0; k < 24; ++k) { pcv[k] = 0.f; pcs[k] = false; }
    pcv[i] = 1.f; pcs[i] = true;
    for (int lvl = maxd; lvl >= 0; --lvl) {
      for (int nidx = 0; nidx < lcnt[lvl]; ++nidx) {
        int node = levels[lvl][nidx];
        if (node == i) continue;
        if (lvl == maxd) { pcv[node] = 1.f; pcs[node] = true; continue; }
        float c = 0.f;
        for (int cidx = 0; cidx < lcnt[lvl+1]; ++cidx) {
          int ch = levels[lvl+1][cidx];
          if (ch >= 3 && node >= ch - 3 && node <= ch - 1) c += pcs[ch] ? pcv[ch] : 0.f;
        }
        if (lvl != 0) { pcv[node] = c; pcs[node] = true; }
      }
    }
    int A = 0;
    int sidx = H.n;
    for (int lvl = 1; lvl <= maxd; ++lvl) {
      for (int nidx = 0; nidx < lcnt[lvl]; ++nidx) {
        int node = levels[lvl][nidx];
        H.anc[sidx][A] = spine[node];
        H.cnt[sidx][A] = pcs[node] ? pcv[node] : 1.f;
        A++;
      }
    }
    if (A == 0) continue;
    H.pos[sidx] = pos; H.A[sidx] = A; H.rowbase[sidx] = rb; rb += A;
    H.n++;
  }
  H.totalRows = rb;
  H.Tmax = 0;
  for (int s = 0; s < H.n; ++s) if (H.A[s] > H.Tmax) H.Tmax = H.A[s];
  int vals[128], nv = 0;
  for (int s = 0; s < H.n; ++s) {
    vals[nv++] = H.pos[s];
    for (int a = 0; a < H.A[s]; ++a) vals[nv++] = H.anc[s][a];
  }
  H.nu = 0;
  for (int i = 0; i < nv; ++i) {
    bool seen = false;
    for (int u = 0; u < H.nu; ++u) if (H.upos[u] == vals[i]) { seen = true; break; }
    if (!seen) H.upos[H.nu++] = vals[i];
  }
  for (int i = 0; i < H.nu; ++i)
    for (int j2 = i + 1; j2 < H.nu; ++j2)
      if (H.upos[j2] < H.upos[i]) { int t = H.upos[i]; H.upos[i] = H.upos[j2]; H.upos[j2] = t; }
  auto uidx = [&](int v) { for (int u = 0; u < H.nu; ++u) if (H.upos[u] == v) return u; return 0; };
  for (int s = 0; s < H.n; ++s) {
    H.up_of_s[s] = uidx(H.pos[s]);
    for (int a = 0; a < H.A[s]; ++a) {
      int rr = H.rowbase[s] + a;
      H.s_of_rr[rr] = s; H.a_of_rr[rr] = a; H.ua_of_rr[rr] = uidx(H.anc[s][a]);
    }
  }
  return H;
}

// ---------------- device helpers ----------------

__device__ __forceinline__ float wred(float v) {
  #pragma unroll
  for (int off = 32; off; off >>= 1) v += __shfl_xor(v, off);
  return v;
}

__device__ __forceinline__ float dot4(vf4 a, vf4 b) {
  return a.x * b.x + a.y * b.y + a.z * b.z + a.w * b.w;
}

__device__ __forceinline__ void do_copy(const vf4* __restrict__ src, vf4* __restrict__ dst,
                                        int q, int nc, int start4, int n4) {
  for (int i = q * 256 + threadIdx.x; i < n4; i += nc * 256) {
    vf4 v = __builtin_nontemporal_load(&src[start4 + i]);
    __builtin_nontemporal_store(v, &dst[start4 + i]);
  }
}

// ---------------- kernel 1: T matmul + pw-prep (+copy) ----------------
// mains 0..1279 (128 j-tiles x 10 row-tiles), block 1280 = prep, 2048 carriers.
__global__ __launch_bounds__(256, 4) void k_T(SDesc sd, const float* __restrict__ x,
    const float* __restrict__ msg_w, float* __restrict__ T,
    const float* __restrict__ w1, const float* __restrict__ b1,
    const float* __restrict__ w2, const float* __restrict__ b2, float* __restrict__ wout,
    const vf4* __restrict__ csrc, vf4* __restrict__ cdst, int cstart, int cn) {
  int p = blockIdx.x;
  const int NMAIN = 1280;
  if (p > NMAIN) { do_copy(csrc, cdst, p - NMAIN - 1, 2048, cstart, cn); return; }
  if (p == NMAIN) {
    int t = threadIdx.x;
    int s = t >> 3, a = t & 7;
    if (t < 64 && s < sd.n && a < sd.A[s]) {
      float v = sd.cnt[s][a];
      float acc = 0.f;
      for (int i = 0; i < 64; ++i) {
        float h = v * w1[i] + b1[i];
        if (h > 0.f) acc += h * w2[i];
      }
      float o = acc + b2[0];
      wout[s * 8 + a] = (o > 0.f) ? (o + log1pf(expf(-o))) : log1pf(expf(o));
    }
    return;
  }
  int q = p % 128, rt = p / 128;          // rt 0..9
  int jt = (q & 7) * 16 + (q >> 3);       // XCD-pinned
  int wave = threadIdx.x >> 6, lane = threadIdx.x & 63;
  int jc0 = jt * 16 + wave * 4;
  const vf4* mw4 = (const vf4*)msg_w;
  size_t wb0 = (size_t)((jc0 + 0) & 1023) * 512 + ((size_t)((jc0 + 0) >> 10) << 8);
  size_t wb1 = (size_t)((jc0 + 1) & 1023) * 512 + ((size_t)((jc0 + 1) >> 10) << 8);
  size_t wb2 = (size_t)((jc0 + 2) & 1023) * 512 + ((size_t)((jc0 + 2) >> 10) << 8);
  size_t wb3 = (size_t)((jc0 + 3) & 1023) * 512 + ((size_t)((jc0 + 3) >> 10) << 8);
  vf4 tw0[4], tw1[4], tw2[4], tw3[4];
  #pragma unroll
  for (int c = 0; c < 4; ++c) {
    tw0[c] = mw4[wb0 + c * 64 + lane];
    tw1[c] = mw4[wb1 + c * 64 + lane];
    tw2[c] = mw4[wb2 + c * 64 + lane];
    tw3[c] = mw4[wb3 + c * 64 + lane];
  }
  const vf4* x4 = (const vf4*)x;
  #pragma unroll 2
  for (int r = 0; r < 8; ++r) {
    int row = rt * 8 + r; int uq = row >> 3, bb = row & 7;
    size_t rb4 = ((size_t)bb * SEQ + sd.upos[uq]) * 256;
    vf4 a0 = x4[rb4 + 0 * 64 + lane], a1 = x4[rb4 + 1 * 64 + lane];
    vf4 a2 = x4[rb4 + 2 * 64 + lane], a3 = x4[rb4 + 3 * 64 + lane];
    float s0 = dot4(tw0[0], a0) + dot4(tw0[1], a1) + dot4(tw0[2], a2) + dot4(tw0[3], a3);
    float s1 = dot4(tw1[0], a0) + dot4(tw1[1], a1) + dot4(tw1[2], a2) + dot4(tw1[3], a3);
    float s2 = dot4(tw2[0], a0) + dot4(tw2[1], a1) + dot4(tw2[2], a2) + dot4(tw2[3], a3);
    float s3 = dot4(tw3[0], a0) + dot4(tw3[1], a1) + dot4(tw3[2], a2) + dot4(tw3[3], a3);
    s0 = wred(s0); s1 = wred(s1); s2 = wred(s2); s3 = wred(s3);
    if (lane == 0) {
      float* tp = T + (size_t)row * 2048 + jc0;
      tp[0] = s0; tp[1] = s1; tp[2] = s2; tp[3] = s3;
    }
  }
}

// ---------------- kernel 2: LN/gelu/scale (+copy) ----------------
__global__ __launch_bounds__(256) void k_ln(SDesc sd, const float* __restrict__ ln_g,
    const float* __restrict__ ln_b, const float* __restrict__ msg_b,
    const float* __restrict__ wsc, const float* __restrict__ T, float* __restrict__ mseq,
    const vf4* __restrict__ csrc, vf4* __restrict__ cdst, int cstart, int cn) {
  int p = blockIdx.x;
  if (p >= 240) { do_copy(csrc, cdst, p - 240, 2048, cstart, cn); return; }
  int rr = p >> 3, bb = p & 7;
  int s = sd.s_of_rr[rr], aa = sd.a_of_rr[rr];
  int ua = sd.ua_of_rr[rr], up = sd.up_of_s[s];
  float wmul = wsc[s * 8 + aa];
  const vf4* Tl = (const vf4*)(T + ((size_t)ua * 8 + bb) * 2048);
  const vf4* Tr = (const vf4*)(T + ((size_t)up * 8 + bb) * 2048 + 1024);
  const vf4* mb = (const vf4*)msg_b;
  int t = threadIdx.x;
  vf4 vl = Tl[t], vr = Tr[t], vb = mb[t];
  vf4 v; v.x = vl.x + vr.x + vb.x; v.y = vl.y + vr.y + vb.y;
  v.z = vl.z + vr.z + vb.z; v.w = vl.w + vr.w + vb.w;
  float sum = v.x + v.y + v.z + v.w;
  float sq  = v.x * v.x + v.y * v.y + v.z * v.z + v.w * v.w;
  #pragma unroll
  for (int off = 32; off; off >>= 1) { sum += __shfl_xor(sum, off); sq += __shfl_xor(sq, off); }
  __shared__ float s1m[4], s2m[4];
  int wave = t >> 6, lane = t & 63;
  if (lane == 0) { s1m[wave] = sum; s2m[wave] = sq; }
  __syncthreads();
  sum = s1m[0] + s1m[1] + s1m[2] + s1m[3];
  sq  = s2m[0] + s2m[1] + s2m[2] + s2m[3];
  float mu  = sum * (1.f / 1024.f);
  float var = sq * (1.f / 1024.f) - mu * mu;
  float inv = rsqrtf(var + 1e-5f);
  vf4 g4 = ((const vf4*)ln_g)[t];
  vf4 b4 = ((const vf4*)ln_b)[t];
  float o[4]  = {v.x, v.y, v.z, v.w};
  float gg[4] = {g4.x, g4.y, g4.z, g4.w};
  float bb2[4] = {b4.x, b4.y, b4.z, b4.w};
  #pragma unroll
  for (int i = 0; i < 4; ++i) {
    float u = (o[i] - mu) * inv * gg[i] + bb2[i];
    float ge = 0.5f * u * (1.f + erff(u * 0.70710678118654752f));
    o[i] = ge * wmul;
  }
  vf4 ov; ov.x = o[0]; ov.y = o[1]; ov.z = o[2]; ov.w = o[3];
  ((vf4*)(mseq + (size_t)p * DIM))[t] = ov;
}

// ---------------- kernel 3: gi (gate-triple) + fused step-0 (+copy) ----------------
// mains 0..1279: 256 j-tiles(4 j, 1/wave) x 5 row-tiles(48 rows), LDS-staged rows.
// Wave owns j and computes r,z,n for it -> step-0 (a==0 && A==Tmax) fused race-free.
__global__ __launch_bounds__(256, 4) void k_gi(SDesc sd, const float* __restrict__ mseq,
    const float* __restrict__ wih, const float* __restrict__ bih,
    const float* __restrict__ bhh, float* __restrict__ gi, float* __restrict__ h1,
    const vf4* __restrict__ csrc, vf4* __restrict__ cdst, int cstart, int cn) {
  int p = blockIdx.x;
  const int NMAIN = 1280;
  if (p >= NMAIN) { do_copy(csrc, cdst, p - NMAIN, 2048, cstart, cn); return; }
  int q = p % 256, rt = p / 256;          // rt 0..4 (48 rows each)
  int jt = (q & 7) * 32 + (q >> 3);       // 0..255, XCD-pinned
  int wave = threadIdx.x >> 6, lane = threadIdx.x & 63;
  int j = jt * 4 + wave;                  // 0..1023

  const vf4* wp4 = (const vf4*)wih;
  vf4 wr[4], wz[4], wn[4];
  #pragma unroll
  for (int c = 0; c < 4; ++c) {
    wr[c] = wp4[(size_t)j * 256 + c * 64 + lane];
    wz[c] = wp4[(size_t)(1024 + j) * 256 + c * 64 + lane];
    wn[c] = wp4[(size_t)(2048 + j) * 256 + c * 64 + lane];
  }
  float bi_r = bih[j], bi_z = bih[1024 + j], bi_n = bih[2048 + j];
  float bh_r = bhh[j], bh_z = bhh[1024 + j], bh_n = bhh[2048 + j];

  __shared__ float lrow[8][1024];         // 32 KB
  int rowbase = rt * 48;
  for (int ch = 0; ch < 6; ++ch) {
    __syncthreads();
    for (int idx = threadIdx.x; idx < 8 * 256; idx += 256) {
      int r = idx >> 8, c = idx & 255;
      ((vf4*)lrow[r])[c] = ((const vf4*)(mseq + (size_t)(rowbase + ch * 8 + r) * DIM))[c];
    }
    __syncthreads();
    for (int r = 0; r < 8; ++r) {
      int row = rowbase + ch * 8 + r;
      const vf4* hp = (const vf4*)lrow[r];
      vf4 a0 = hp[0 * 64 + lane], a1 = hp[1 * 64 + lane];
      vf4 a2 = hp[2 * 64 + lane], a3 = hp[3 * 64 + lane];
      float sr = dot4(wr[0], a0) + dot4(wr[1], a1) + dot4(wr[2], a2) + dot4(wr[3], a3);
      float sz = dot4(wz[0], a0) + dot4(wz[1], a1) + dot4(wz[2], a2) + dot4(wz[3], a3);
      float sn = dot4(wn[0], a0) + dot4(wn[1], a1) + dot4(wn[2], a2) + dot4(wn[3], a3);
      sr = wred(sr); sz = wred(sz); sn = wred(sn);
      if (lane == 0) {
        sr += bi_r; sz += bi_z; sn += bi_n;
        float* gp = gi + (size_t)row * 3072;
        gp[j] = sr; gp[1024 + j] = sz; gp[2048 + j] = sn;
        int rr = row >> 3;
        int s = sd.s_of_rr[rr];
        if (sd.a_of_rr[rr] == 0 && sd.A[s] == sd.Tmax) {
          // global step 0: h==0 -> gh = b_hh; h1 = (1-z)*n
          float rg = 1.f / (1.f + expf(-(sr + bh_r)));
          float zg = 1.f / (1.f + expf(-(sz + bh_z)));
          float ng = tanhf(sn + rg * bh_n);
          h1[(size_t)(s * 8 + (row & 7)) * DIM + j] = (1.f - zg) * ng;
        }
      }
    }
  }
}

// ---------------- kernel 4..7: GRU step t=1..4 (+copy) ----------------
// mains 0..1791: 7 structs x 256 j-tiles (1 j per wave).
__global__ __launch_bounds__(256, 4) void k_step(SDesc sd, int t,
    const float* __restrict__ whh, const float* __restrict__ bhh,
    const float* __restrict__ gi, const float* __restrict__ hold, float* __restrict__ hnew,
    const vf4* __restrict__ csrc, vf4* __restrict__ cdst, int cstart, int cn) {
  int p = blockIdx.x;
  const int NMAIN = 7 * 256;
  if (p >= NMAIN) { do_copy(csrc, cdst, p - NMAIN, 1536, cstart, cn); return; }
  int q = p & 255, s = p >> 8;
  int jt = (q & 7) * 32 + (q >> 3);       // 0..255, XCD-pinned across structs & steps
  int t0 = sd.Tmax - sd.A[s];
  if (t < t0) return;
  int a = t - t0;

  int wave = threadIdx.x >> 6, lane = threadIdx.x & 63;
  int j = jt * 4 + wave;
  int girow0 = (sd.rowbase[s] + a) * 8;

  if (a == 0) {
    if (lane < 8) {
      int r = lane;
      const float* gp = gi + (size_t)(girow0 + r) * 3072;
      float rg = 1.f / (1.f + expf(-(gp[j] + bhh[j])));
      float zg = 1.f / (1.f + expf(-(gp[1024 + j] + bhh[1024 + j])));
      float ng = tanhf(gp[2048 + j] + rg * bhh[2048 + j]);
      hnew[(size_t)(s * 8 + r) * DIM + j] = (1.f - zg) * ng;
    }
    return;
  }

  const vf4* wp4 = (const vf4*)whh;
  vf4 wr[4], wz[4], wn[4];
  #pragma unroll
  for (int c = 0; c < 4; ++c) {
    wr[c] = wp4[(size_t)j * 256 + c * 64 + lane];
    wz[c] = wp4[(size_t)(1024 + j) * 256 + c * 64 + lane];
    wn[c] = wp4[(size_t)(2048 + j) * 256 + c * 64 + lane];
  }
  float bj_r = bhh[j], bj_z = bhh[1024 + j], bj_n = bhh[2048 + j];
  const vf4* h4 = (const vf4*)hold;
  #pragma unroll 2
  for (int r = 0; r < 8; ++r) {
    int srow = s * 8 + r;
    size_t rb4 = (size_t)srow * 256;
    const float* gp = gi + (size_t)(girow0 + r) * 3072;
    float gir = gp[j], giz = gp[1024 + j], gin = gp[2048 + j];
    vf4 a0 = h4[rb4 + 0 * 64 + lane], a1 = h4[rb4 + 1 * 64 + lane];
    vf4 a2 = h4[rb4 + 2 * 64 + lane], a3 = h4[rb4 + 3 * 64 + lane];
    float ar = dot4(wr[0], a0) + dot4(wr[1], a1) + dot4(wr[2], a2) + dot4(wr[3], a3);
    float az = dot4(wz[0], a0) + dot4(wz[1], a1) + dot4(wz[2], a2) + dot4(wz[3], a3);
    float an = dot4(wn[0], a0) + dot4(wn[1], a1) + dot4(wn[2], a2) + dot4(wn[3], a3);
    ar = wred(ar); az = wred(az); an = wred(an);
    if (lane == 0) {
      float rg = 1.f / (1.f + expf(-(gir + ar + bj_r)));
      float zg = 1.f / (1.f + expf(-(giz + az + bj_z)));
      float ng = tanhf(gin + rg * (an + bj_n));
      float ho = hold[(size_t)srow * DIM + j];
      hnew[(size_t)srow * DIM + j] = (1.f - zg) * ng + zg * ho;
    }
  }
}

// ---------------- kernel 8: gate + final blend ----------------
// 896 blocks = 128 j-tiles(8 j, 2/wave) x 7 row-tiles(8 rows).
__global__ __launch_bounds__(256, 4) void k_gate(SDesc sd, const float* __restrict__ x,
    const float* __restrict__ gw, const float* __restrict__ gb,
    const float* __restrict__ hfin, float* __restrict__ out) {
  int p = blockIdx.x;
  int q = p % 128, rt = p / 128;          // rt 0..6
  int jt = (q & 7) * 16 + (q >> 3);       // 0..127

  int wave = threadIdx.x >> 6, lane = threadIdx.x & 63;
  int j0 = jt * 8 + wave * 2;
  const vf4* g4p = (const vf4*)gw;
  vf4 wL0[4], wR0[4], wL1[4], wR1[4];
  #pragma unroll
  for (int c = 0; c < 4; ++c) {
    wL0[c] = g4p[(size_t)(j0 + 0) * 512 + c * 64 + lane];
    wR0[c] = g4p[(size_t)(j0 + 0) * 512 + 256 + c * 64 + lane];
    wL1[c] = g4p[(size_t)(j0 + 1) * 512 + c * 64 + lane];
    wR1[c] = g4p[(size_t)(j0 + 1) * 512 + 256 + c * 64 + lane];
  }
  const vf4* h4 = (const vf4*)hfin;
  const vf4* x4 = (const vf4*)x;
  #pragma unroll 2
  for (int r = 0; r < 8; ++r) {
    int row = rt * 8 + r; int s = row >> 3, bb = row & 7;
    size_t ab4 = (size_t)row * 256;
    size_t xb4 = ((size_t)bb * SEQ + sd.pos[s]) * 256;
    vf4 a0 = h4[ab4 + 0 * 64 + lane], a1 = h4[ab4 + 1 * 64 + lane];
    vf4 a2 = h4[ab4 + 2 * 64 + lane], a3 = h4[ab4 + 3 * 64 + lane];
    vf4 x0 = x4[xb4 + 0 * 64 + lane], x1 = x4[xb4 + 1 * 64 + lane];
    vf4 x2 = x4[xb4 + 2 * 64 + lane], x3 = x4[xb4 + 3 * 64 + lane];
    float s0 = dot4(wL0[0], a0) + dot4(wL0[1], a1) + dot4(wL0[2], a2) + dot4(wL0[3], a3)
             + dot4(wR0[0], x0) + dot4(wR0[1], x1) + dot4(wR0[2], x2) + dot4(wR0[3], x3);
    float s1 = dot4(wL1[0], a0) + dot4(wL1[1], a1) + dot4(wL1[2], a2) + dot4(wL1[3], a3)
             + dot4(wR1[0], x0) + dot4(wR1[1], x1) + dot4(wR1[2], x2) + dot4(wR1[3], x3);
    s0 = wred(s0); s1 = wred(s1);
    if (lane == 0) {
      #pragma unroll
      for (int jj = 0; jj < 2; ++jj) {
        int j = j0 + jj;
        float sv = jj ? s1 : s0;
        float g = 1.f / (1.f + expf(-(sv + gb[j])));
        float agg = hfin[(size_t)row * DIM + j];
        float hc  = x[((size_t)bb * SEQ + sd.pos[s]) * DIM + j];
        out[((size_t)bb * SEQ + sd.pos[s]) * DIM + j] = g * agg + (1.f - g) * hc;
      }
    }
  }
}

// ---------------- launch ----------------

extern "C" void kernel_launch(void* const* d_in, const int* in_sizes, int n_in,
                              void* d_out, int out_size, void* d_ws, size_t ws_size,
                              hipStream_t stream) {
  const float* x      = (const float*)d_in[0];
  const float* pw_w1  = (const float*)d_in[1];
  const float* pw_b1  = (const float*)d_in[2];
  const float* pw_w2  = (const float*)d_in[3];
  const float* pw_b2  = (const float*)d_in[4];
  const float* msg_w  = (const float*)d_in[5];
  const float* msg_b  = (const float*)d_in[6];
  const float* ln_g   = (const float*)d_in[7];
  const float* ln_b   = (const float*)d_in[8];
  const float* w_ih   = (const float*)d_in[9];
  const float* w_hh   = (const float*)d_in[10];
  const float* b_ih   = (const float*)d_in[11];
  const float* b_hh   = (const float*)d_in[12];
  const float* gate_w = (const float*)d_in[13];
  const float* gate_b = (const float*)d_in[14];
  float* out = (float*)d_out;
  float* ws  = (float*)d_ws;

  SDesc sd = build_structs();          // n=7, Tmax=5, totalRows=30, nu=10 for S=8192

  float* wout = ws;                                    // 64
  float* T    = wout + 64;                             // 80*2048
  float* mseq = T + (size_t)sd.nu * 8 * 2048;          // 240*1024
  float* gi   = mseq + (size_t)240 * DIM;              // 240*3072
  float* h0   = gi + (size_t)240 * 3072;               // 56*1024
  float* h1   = h0 + (size_t)sd.n * 8 * DIM;           // 56*1024

  const vf4* x4 = (const vf4*)x;
  vf4* out4 = (vf4*)out;
  const int TOTAL4 = (NBATCH * SEQ * DIM) / 4;         // 16,777,216
  const int c_big = 3300000;                           // k_T, k_ln, k_gi
  const int rem = TOTAL4 - 3 * c_big;                  // 6,877,216
  const int c_s = rem / 4;                             // 1,719,304

  int off = 0;
  k_T<<<1281 + 2048, 256, 0, stream>>>(sd, x, msg_w, T, pw_w1, pw_b1, pw_w2, pw_b2, wout,
                                       x4, out4, off, c_big);
  off += c_big;

  k_ln<<<240 + 2048, 256, 0, stream>>>(sd, ln_g, ln_b, msg_b, wout, T, mseq,
                                       x4, out4, off, c_big);
  off += c_big;

  k_gi<<<1280 + 2048, 256, 0, stream>>>(sd, mseq, w_ih, b_ih, b_hh, gi, h1,
                                        x4, out4, off, c_big);
  off += c_big;

  // GRU steps t=1..4 (t=0 fused into k_gi; h parity: t writes (t&1)?h0:h1)
  for (int t = 1; t <= 4; ++t) {
    const float* hr = (t & 1) ? h1 : h0;
    float*       hw = (t & 1) ? h0 : h1;
    int cnt = (t == 4) ? (TOTAL4 - off) : c_s;
    k_step<<<1792 + 1536, 256, 0, stream>>>(sd, t, w_hh, b_hh, gi, hr, hw,
                                            x4, out4, off, cnt);
    off += cnt;
  }
  // t=4 writes h1 -> final state in h1
  k_gate<<<896, 256, 0, stream>>>(sd, x, gate_w, gate_b, h1, out);

  (void)in_sizes; (void)n_in; (void)out_size; (void)ws_size;
}